// Round 4
// baseline (131.116 us; speedup 1.0000x reference)
//
#include <hip/hip_runtime.h>

// Coords2Grid: libmolgrid-style density splat.
// out[t, x, y, z] = sum_n f(d(n, xyz)/r_n) * types[n, t]
//   f(u) = exp(-2 u^2)                 u < 1
//        = e^-2 (4u^2 - 12u + 9)       1 <= u < 1.5
//        = 0                           otherwise
#define GR    48
#define GR2   (GR * GR)
#define GR3   (GR * GR * GR)
#define NA    800
#define NT    28
#define NTP   29                    // padded type stride in LDS (bank-conflict-free)
#define RESF  0.5f
#define HALF_DIM 11.75f
#define INV_E2 0.13533528323661270f
#define TILE  4
#define NTPD  (GR / TILE)           // 12 tiles per dim
#define NBLK  (NTPD * NTPD * NTPD)  // 1728 blocks
#define NW    4                     // waves per block

__global__ __launch_bounds__(256) void c2g_kernel(
    const float* __restrict__ center,
    const float* __restrict__ coords,
    const float* __restrict__ types,
    const float* __restrict__ radii,
    float* __restrict__ out)
{
    __shared__ float s_ax[NA], s_ay[NA], s_az[NA], s_ir2[NA];
    __shared__ int   s_ai[NA];
    __shared__ int   s_cnt;
    __shared__ float s_acc[64 * NTP];   // [point][type], padded stride 29

    const int tid  = threadIdx.x;
    const int lane = tid & 63;          // point within tile
    const int wave = tid >> 6;          // atom-loop stripe
    const int b    = blockIdx.x;
    const int tz   = b % NTPD;
    const int ty   = (b / NTPD) % NTPD;
    const int tx   = b / (NTPD * NTPD);

    const float ox = center[0] - HALF_DIM;
    const float oy = center[1] - HALF_DIM;
    const float oz = center[2] - HALF_DIM;

    const float bxlo = ox + tx * (TILE * RESF), bxhi = bxlo + (TILE - 1) * RESF;
    const float bylo = oy + ty * (TILE * RESF), byhi = bylo + (TILE - 1) * RESF;
    const float bzlo = oz + tz * (TILE * RESF), bzhi = bzlo + (TILE - 1) * RESF;

    if (tid == 0) s_cnt = 0;
    #pragma unroll
    for (int i = 0; i < 64 * NTP / 256 + 1; ++i) {
        int idx = i * 256 + tid;
        if (idx < 64 * NTP) s_acc[idx] = 0.0f;
    }
    __syncthreads();

    // Prefilter: atoms whose 1.5r sphere reaches the tile's point bbox.
    for (int a = tid; a < NA; a += 256) {
        float ax = coords[3 * a + 0];
        float ay = coords[3 * a + 1];
        float az = coords[3 * a + 2];
        float r  = radii[a];
        float cut = 1.5f * r;
        float ddx = ax - fminf(fmaxf(ax, bxlo), bxhi);
        float ddy = ay - fminf(fmaxf(ay, bylo), byhi);
        float ddz = az - fminf(fmaxf(az, bzlo), bzhi);
        float d2 = fmaf(ddx, ddx, fmaf(ddy, ddy, ddz * ddz));
        if (d2 < cut * cut) {
            int p = atomicAdd(&s_cnt, 1);
            s_ax[p] = ax; s_ay[p] = ay; s_az[p] = az;
            s_ir2[p] = 1.0f / (r * r);
            s_ai[p] = a;
        }
    }
    __syncthreads();
    const int cnt = s_cnt;

    // Lane -> cell within tile (z fastest).
    const int lz = lane & 3;
    const int ly = (lane >> 2) & 3;
    const int lx = lane >> 4;
    const float gx = bxlo + lx * RESF;
    const float gy = bylo + ly * RESF;
    const float gz = bzlo + lz * RESF;

    float acc[NT];
    #pragma unroll
    for (int t = 0; t < NT; ++t) acc[t] = 0.0f;

    // Atom loop split across the 4 waves.
    for (int k = wave; k < cnt; k += NW) {
        float dx = gx - s_ax[k];
        float dy = gy - s_ay[k];
        float dz = gz - s_az[k];
        float ir2 = s_ir2[k];
        float d2 = fmaf(dx, dx, fmaf(dy, dy, dz * dz));
        float dr2 = d2 * ir2;
        bool act = dr2 < 2.25f;
        if (!__any(act)) continue;

        float g  = __expf(-2.0f * dr2);
        float dr = sqrtf(dr2);
        float q  = INV_E2 * fmaf(4.0f, dr2, fmaf(-12.0f, dr, 9.0f));
        float val = (dr2 < 1.0f) ? g : q;
        val = act ? val : 0.0f;

        int a = __builtin_amdgcn_readfirstlane(s_ai[k]);
        const float4* tp = (const float4*)(types + a * NT);  // uniform -> s_load
        #pragma unroll
        for (int q4 = 0; q4 < NT / 4; ++q4) {
            float4 tv = tp[q4];
            acc[4 * q4 + 0] = fmaf(val, tv.x, acc[4 * q4 + 0]);
            acc[4 * q4 + 1] = fmaf(val, tv.y, acc[4 * q4 + 1]);
            acc[4 * q4 + 2] = fmaf(val, tv.z, acc[4 * q4 + 2]);
            acc[4 * q4 + 3] = fmaf(val, tv.w, acc[4 * q4 + 3]);
        }
    }

    // Cross-wave reduce (stride-29 -> conflict-free).
    #pragma unroll
    for (int t = 0; t < NT; ++t)
        atomicAdd(&s_acc[lane * NTP + t], acc[t]);
    __syncthreads();

    // Store: 1792 outputs, 7 per thread.
    #pragma unroll
    for (int i = 0; i < 7; ++i) {
        int idx = i * 256 + tid;         // < 1792
        int t = idx >> 6;
        int p = idx & 63;
        int pz = p & 3, py = (p >> 2) & 3, px = p >> 4;
        int gidx = ((tx * TILE + px) * GR + (ty * TILE + py)) * GR + tz * TILE + pz;
        out[t * GR3 + gidx] = s_acc[p * NTP + t];
    }
}

extern "C" void kernel_launch(void* const* d_in, const int* in_sizes, int n_in,
                              void* d_out, int out_size, void* d_ws, size_t ws_size,
                              hipStream_t stream) {
    const float* center = (const float*)d_in[0];
    const float* coords = (const float*)d_in[1];
    const float* types  = (const float*)d_in[2];
    const float* radii  = (const float*)d_in[3];
    float* out = (float*)d_out;

    c2g_kernel<<<dim3(NBLK), dim3(256), 0, stream>>>(center, coords, types, radii, out);
}

// Round 5
// 86.559 us; speedup vs baseline: 1.5148x; 1.5148x over previous
//
#include <hip/hip_runtime.h>

// Coords2Grid: libmolgrid-style density splat.
// out[t, x, y, z] = sum_n f(d(n, xyz)/r_n) * types[n, t]
//   f(u) = exp(-2 u^2)                 u < 1
//        = e^-2 (4u^2 - 12u + 9)       1 <= u < 1.5
//        = 0                           otherwise
#define GR    48
#define GR3   (GR * GR * GR)
#define NA    800
#define NT    28
#define RESF  0.5f
#define HALF_DIM 11.75f
#define INV_E2 0.13533528323661270f
#define TILE  4
#define NTPD  (GR / TILE)           // 12
#define NBLK  (NTPD * NTPD * NTPD)  // 1728
#define KB    64                    // atoms per batch
#define TPW   (NT / 4)              // 7 types per wave

__global__ __launch_bounds__(256) void c2g_kernel(
    const float* __restrict__ center,
    const float* __restrict__ coords,
    const float* __restrict__ types,
    const float* __restrict__ radii,
    float* __restrict__ out)
{
    __shared__ float s_ax[NA], s_ay[NA], s_az[NA], s_ir2[NA];
    __shared__ int   s_ai[NA];
    __shared__ int   s_cnt;
    __shared__ float s_val[KB * 64];     // [atom-in-batch][cell]

    const int tid  = threadIdx.x;
    const int lane = tid & 63;
    const int w    = tid >> 6;
    const int b    = blockIdx.x;
    const int tz   = b % NTPD;
    const int ty   = (b / NTPD) % NTPD;
    const int tx   = b / (NTPD * NTPD);

    const float ox = center[0] - HALF_DIM;
    const float oy = center[1] - HALF_DIM;
    const float oz = center[2] - HALF_DIM;

    const float bxlo = ox + tx * (TILE * RESF), bxhi = bxlo + (TILE - 1) * RESF;
    const float bylo = oy + ty * (TILE * RESF), byhi = bylo + (TILE - 1) * RESF;
    const float bzlo = oz + tz * (TILE * RESF), bzhi = bzlo + (TILE - 1) * RESF;

    if (tid == 0) s_cnt = 0;
    __syncthreads();

    // ---- Prefilter: ballot-compacted (1 LDS atomic per wave per pass) ----
    for (int a0 = 0; a0 < NA; a0 += 256) {
        int a = a0 + tid;
        bool accept = false;
        float ax = 0.f, ay = 0.f, az = 0.f, r = 1.f;
        if (a < NA) {
            ax = coords[3 * a + 0];
            ay = coords[3 * a + 1];
            az = coords[3 * a + 2];
            r  = radii[a];
            float cut = 1.5f * r;
            float ddx = ax - fminf(fmaxf(ax, bxlo), bxhi);
            float ddy = ay - fminf(fmaxf(ay, bylo), byhi);
            float ddz = az - fminf(fmaxf(az, bzlo), bzhi);
            float d2 = fmaf(ddx, ddx, fmaf(ddy, ddy, ddz * ddz));
            accept = d2 < cut * cut;
        }
        unsigned long long m = __ballot(accept);
        if (m) {                               // wave-uniform
            int base = 0;
            if (lane == 0) base = atomicAdd(&s_cnt, __popcll(m));
            base = __shfl(base, 0);
            if (accept) {
                int p = base + __popcll(m & ((1ull << lane) - 1ull));
                s_ax[p] = ax; s_ay[p] = ay; s_az[p] = az;
                s_ir2[p] = 1.0f / (r * r);
                s_ai[p] = a;
            }
        }
    }
    __syncthreads();
    const int cnt = s_cnt;

    // Lane -> cell within tile (z fastest).
    const int lz = lane & 3;
    const int ly = (lane >> 2) & 3;
    const int lx = lane >> 4;
    const float gx = bxlo + lx * RESF;
    const float gy = bylo + ly * RESF;
    const float gz = bzlo + lz * RESF;

    float acc[TPW];
    #pragma unroll
    for (int j = 0; j < TPW; ++j) acc[j] = 0.0f;
    const int tbase = w * TPW;               // this wave's type slice

    for (int k0 = 0; k0 < cnt; k0 += KB) {
        // ---- Stage A: wave w computes val rows [w*16, w*16+16) ----
        #pragma unroll
        for (int j = 0; j < 16; ++j) {
            int row = w * 16 + j;
            int k = k0 + row;
            float val = 0.0f;
            if (k < cnt) {                   // wave-uniform
                float dx = gx - s_ax[k];
                float dy = gy - s_ay[k];
                float dz = gz - s_az[k];
                float d2 = fmaf(dx, dx, fmaf(dy, dy, dz * dz));
                float dr2 = d2 * s_ir2[k];
                float g  = __expf(-2.0f * dr2);
                float dr = sqrtf(dr2);
                float q  = INV_E2 * fmaf(4.0f, dr2, fmaf(-12.0f, dr, 9.0f));
                val = (dr2 < 1.0f) ? g : ((dr2 < 2.25f) ? q : 0.0f);
            }
            s_val[row * 64 + lane] = val;
        }
        __syncthreads();

        // ---- Stage B: 7-type GEMV slice over the batch ----
        const int kmax = (cnt - k0 < KB) ? (cnt - k0) : KB;
        #pragma unroll 4
        for (int k = 0; k < kmax; ++k) {
            float v = s_val[k * 64 + lane];
            int a = __builtin_amdgcn_readfirstlane(s_ai[k0 + k]);
            const float* trow = types + a * NT + tbase;
            #pragma unroll
            for (int j = 0; j < TPW; ++j)
                acc[j] = fmaf(v, trow[j], acc[j]);
        }
        __syncthreads();
    }

    // ---- Store: wave w writes its 7 type-planes for its lane's cell ----
    const int gidx = ((tx * TILE + lx) * GR + (ty * TILE + ly)) * GR + tz * TILE + lz;
    #pragma unroll
    for (int j = 0; j < TPW; ++j)
        out[(tbase + j) * GR3 + gidx] = acc[j];
}

extern "C" void kernel_launch(void* const* d_in, const int* in_sizes, int n_in,
                              void* d_out, int out_size, void* d_ws, size_t ws_size,
                              hipStream_t stream) {
    const float* center = (const float*)d_in[0];
    const float* coords = (const float*)d_in[1];
    const float* types  = (const float*)d_in[2];
    const float* radii  = (const float*)d_in[3];
    float* out = (float*)d_out;

    c2g_kernel<<<dim3(NBLK), dim3(256), 0, stream>>>(center, coords, types, radii, out);
}

// Round 6
// 74.398 us; speedup vs baseline: 1.7624x; 1.1634x over previous
//
#include <hip/hip_runtime.h>

// Coords2Grid: libmolgrid-style density splat.
// out[t, x, y, z] = sum_n f(d(n, xyz)/r_n) * types[n, t]
//   f(u) = exp(-2 u^2)   u<1 ;  e^-2 (4u^2-12u+9)  1<=u<1.5 ;  0 otherwise
#define GR    48
#define GR2   (GR * GR)
#define GR3   (GR * GR * GR)
#define NA    800
#define NT    28
#define RESF  0.5f
#define HALF_DIM 11.75f
#define INV_E2 0.13533528323661270f

#define TXC   2                     // tile cells in x
#define TYC   2                     // y
#define TZC   16                    // z (16 cells = 64B rows -> coalesced stores)
#define NTX   (GR / TXC)            // 24
#define NTY   (GR / TYC)            // 24
#define NTZ   (GR / TZC)            // 3
#define NBLK  (NTX * NTY * NTZ)     // 1728
#define KB    64                    // atoms per batch
#define TSL   8                     // type-slice width per wave (8,8,8,4-valid)

__global__ __launch_bounds__(256) void c2g_kernel(
    const float* __restrict__ center,
    const float* __restrict__ coords,
    const float* __restrict__ types,
    const float* __restrict__ radii,
    float* __restrict__ out)
{
    __shared__ float s_ax[NA], s_ay[NA], s_az[NA], s_ir2[NA];
    __shared__ int   s_ai[NA];
    __shared__ int   s_cnt;
    __shared__ float s_val[KB * 64];    // [atom-in-batch][cell]
    __shared__ float s_tb[KB * 32];     // [atom-in-batch][type(28, padded 32)]

    const int tid  = threadIdx.x;
    const int lane = tid & 63;
    const int w    = tid >> 6;
    const int b    = blockIdx.x;
    const int tz   = b % NTZ;
    const int ty   = (b / NTZ) % NTY;
    const int tx   = b / (NTZ * NTY);

    const float ox = center[0] - HALF_DIM;
    const float oy = center[1] - HALF_DIM;
    const float oz = center[2] - HALF_DIM;

    const float bxlo = ox + tx * (TXC * RESF), bxhi = bxlo + (TXC - 1) * RESF;
    const float bylo = oy + ty * (TYC * RESF), byhi = bylo + (TYC - 1) * RESF;
    const float bzlo = oz + tz * (TZC * RESF), bzhi = bzlo + (TZC - 1) * RESF;

    if (tid == 0) s_cnt = 0;
    __syncthreads();

    // ---- Prefilter: ballot-compacted (1 LDS atomic per wave per pass) ----
    for (int a0 = 0; a0 < NA; a0 += 256) {
        int a = a0 + tid;
        bool accept = false;
        float ax = 0.f, ay = 0.f, az = 0.f, r = 1.f;
        if (a < NA) {
            ax = coords[3 * a + 0];
            ay = coords[3 * a + 1];
            az = coords[3 * a + 2];
            r  = radii[a];
            float cut = 1.5f * r;
            float ddx = ax - fminf(fmaxf(ax, bxlo), bxhi);
            float ddy = ay - fminf(fmaxf(ay, bylo), byhi);
            float ddz = az - fminf(fmaxf(az, bzlo), bzhi);
            float d2 = fmaf(ddx, ddx, fmaf(ddy, ddy, ddz * ddz));
            accept = d2 < cut * cut;
        }
        unsigned long long m = __ballot(accept);
        if (m) {
            int base = 0;
            if (lane == 0) base = atomicAdd(&s_cnt, __popcll(m));
            base = __shfl(base, 0);
            if (accept) {
                int p = base + __popcll(m & ((1ull << lane) - 1ull));
                s_ax[p] = ax; s_ay[p] = ay; s_az[p] = az;
                s_ir2[p] = 1.0f / (r * r);
                s_ai[p] = a;
            }
        }
    }
    __syncthreads();
    const int cnt = s_cnt;

    // Lane -> cell within 2x2x16 tile (z fastest).
    const int lzz = lane & 15;
    const int ly2 = (lane >> 4) & 1;
    const int lx2 = lane >> 5;
    const float gx = bxlo + lx2 * RESF;
    const float gy = bylo + ly2 * RESF;
    const float gz = bzlo + lzz * RESF;

    float acc[TSL];
    #pragma unroll
    for (int j = 0; j < TSL; ++j) acc[j] = 0.0f;
    const int tbase = w * TSL;           // 0,8,16,24

    for (int k0 = 0; k0 < cnt; k0 += KB) {
        const int kmax = (cnt - k0 < KB) ? (cnt - k0) : KB;

        // ---- Issue type-row loads early (affine addresses, 2 per thread) ----
        float4 tv0 = make_float4(0.f, 0.f, 0.f, 0.f);
        float4 tv1 = tv0;
        {
            int s = tid;                         // slot: row = s>>3, q = s&7
            int row = s >> 3, q = s & 7;
            if (q < 7 && row < kmax)
                tv0 = *(const float4*)(types + s_ai[k0 + row] * NT + q * 4);
            s = tid + 256;
            row = s >> 3; q = s & 7;
            if (q < 7 && row < kmax)
                tv1 = *(const float4*)(types + s_ai[k0 + row] * NT + q * 4);
        }

        // ---- Stage A: wave w computes val for rows [w*16, w*16+16) ----
        #pragma unroll
        for (int j = 0; j < 16; ++j) {
            int row = w * 16 + j;
            float val = 0.0f;
            if (row < kmax) {                    // wave-uniform
                int k = k0 + row;
                float dx = gx - s_ax[k];
                float dy = gy - s_ay[k];
                float dz = gz - s_az[k];
                float d2 = fmaf(dx, dx, fmaf(dy, dy, dz * dz));
                float dr2 = d2 * s_ir2[k];
                float g  = __expf(-2.0f * dr2);
                float dr = sqrtf(dr2);
                float q  = INV_E2 * fmaf(4.0f, dr2, fmaf(-12.0f, dr, 9.0f));
                val = (dr2 < 1.0f) ? g : ((dr2 < 2.25f) ? q : 0.0f);
            }
            s_val[row * 64 + lane] = val;
        }

        // ---- Write staged type rows (loads have had stage A to complete) ----
        {
            int s = tid;
            *(float4*)&s_tb[(s >> 3) * 32 + (s & 7) * 4] = tv0;
            s = tid + 256;
            *(float4*)&s_tb[(s >> 3) * 32 + (s & 7) * 4] = tv1;
        }
        __syncthreads();

        // ---- Stage B: affine-address GEMV slice, fully pipelineable ----
        #pragma unroll 4
        for (int k = 0; k < kmax; ++k) {
            float v = s_val[k * 64 + lane];
            const float* tr = &s_tb[k * 32 + tbase];
            #pragma unroll
            for (int j = 0; j < TSL; ++j)
                acc[j] = fmaf(v, tr[j], acc[j]);
        }
        __syncthreads();
    }

    // ---- Store: wave w writes its type slice; 16 consecutive z per segment ----
    const int gidx = (tx * TXC + lx2) * GR2 + (ty * TYC + ly2) * GR + tz * TZC + lzz;
    #pragma unroll
    for (int j = 0; j < TSL; ++j) {
        int t = tbase + j;
        if (t < NT) out[t * GR3 + gidx] = acc[j];
    }
}

extern "C" void kernel_launch(void* const* d_in, const int* in_sizes, int n_in,
                              void* d_out, int out_size, void* d_ws, size_t ws_size,
                              hipStream_t stream) {
    const float* center = (const float*)d_in[0];
    const float* coords = (const float*)d_in[1];
    const float* types  = (const float*)d_in[2];
    const float* radii  = (const float*)d_in[3];
    float* out = (float*)d_out;

    c2g_kernel<<<dim3(NBLK), dim3(256), 0, stream>>>(center, coords, types, radii, out);
}

// Round 7
// 72.063 us; speedup vs baseline: 1.8195x; 1.0324x over previous
//
#include <hip/hip_runtime.h>

// Coords2Grid: libmolgrid-style density splat.
// out[t, x, y, z] = sum_n f(d(n, xyz)/r_n) * types[n, t]
//   f(u) = exp(-2 u^2)   u<1 ;  e^-2 (4u^2-12u+9)  1<=u<1.5 ;  0 otherwise
#define GR    48
#define GR2   (GR * GR)
#define GR3   (GR * GR * GR)
#define NA    800
#define NT    28
#define RESF  0.5f
#define HALF_DIM 11.75f
#define INV_E2 0.13533528323661270f

#define TXC   2
#define TYC   2
#define TZC   16
#define NTX   (GR / TXC)            // 24
#define NTY   (GR / TYC)            // 24
#define NTZ   (GR / TZC)            // 3
#define NBLK  (NTX * NTY * NTZ)     // 1728
#define KB    64                    // atoms per batch
#define KPAD  80                    // ushort row stride (160B, 16B-aligned)

typedef __attribute__((ext_vector_type(8))) short short8;
typedef __attribute__((ext_vector_type(4))) float floatx4;

__device__ inline unsigned short f2bf(float x) {  // RNE float->bf16 (finite, >=0)
    unsigned u = __builtin_bit_cast(unsigned, x);
    u = (u + 0x7FFFu + ((u >> 16) & 1u)) >> 16;
    return (unsigned short)u;
}

__global__ __launch_bounds__(256) void c2g_kernel(
    const float* __restrict__ center,
    const float* __restrict__ coords,
    const float* __restrict__ types,
    const float* __restrict__ radii,
    float* __restrict__ out)
{
    __shared__ float4 s_atom[NA];              // xyz + 1/r^2
    __shared__ int    s_ai[NA];
    __shared__ int    s_cnt;
    __shared__ unsigned short s_val[64 * KPAD]; // [cell][atom] bf16
    __shared__ unsigned short s_tT[32 * KPAD];  // [type][atom] bf16
    __shared__ float  s_out[64 * 33];           // [cell][type] padded

    const int tid  = threadIdx.x;
    const int lane = tid & 63;
    const int w    = tid >> 6;
    const int b    = blockIdx.x;
    const int tz   = b % NTZ;
    const int ty   = (b / NTZ) % NTY;
    const int tx   = b / (NTZ * NTY);

    const float ox = center[0] - HALF_DIM;
    const float oy = center[1] - HALF_DIM;
    const float oz = center[2] - HALF_DIM;

    const float bxlo = ox + tx * (TXC * RESF), bxhi = bxlo + (TXC - 1) * RESF;
    const float bylo = oy + ty * (TYC * RESF), byhi = bylo + (TYC - 1) * RESF;
    const float bzlo = oz + tz * (TZC * RESF), bzhi = bzlo + (TZC - 1) * RESF;

    if (tid == 0) s_cnt = 0;
    __syncthreads();

    // ---- Prefilter: ballot-compacted ----
    for (int a0 = 0; a0 < NA; a0 += 256) {
        int a = a0 + tid;
        bool accept = false;
        float ax = 0.f, ay = 0.f, az = 0.f, r = 1.f;
        if (a < NA) {
            ax = coords[3 * a + 0];
            ay = coords[3 * a + 1];
            az = coords[3 * a + 2];
            r  = radii[a];
            float cut = 1.5f * r;
            float ddx = ax - fminf(fmaxf(ax, bxlo), bxhi);
            float ddy = ay - fminf(fmaxf(ay, bylo), byhi);
            float ddz = az - fminf(fmaxf(az, bzlo), bzhi);
            float d2 = fmaf(ddx, ddx, fmaf(ddy, ddy, ddz * ddz));
            accept = d2 < cut * cut;
        }
        unsigned long long m = __ballot(accept);
        if (m) {
            int base = 0;
            if (lane == 0) base = atomicAdd(&s_cnt, __popcll(m));
            base = __shfl(base, 0);
            if (accept) {
                int p = base + __popcll(m & ((1ull << lane) - 1ull));
                s_atom[p] = make_float4(ax, ay, az, 1.0f / (r * r));
                s_ai[p] = a;
            }
        }
    }
    __syncthreads();
    const int cnt = s_cnt;

    // Lane -> cell within 2x2x16 tile (z fastest).
    const int lzz = lane & 15;
    const int ly2 = (lane >> 4) & 1;
    const int lx2 = lane >> 5;
    const float gx = bxlo + lx2 * RESF;
    const float gy = bylo + ly2 * RESF;
    const float gz = bzlo + lzz * RESF;

    const int lm = lane & 15;     // MFMA row/col within tile
    const int lg = lane >> 4;     // MFMA k-group

    floatx4 acc0 = {0.f, 0.f, 0.f, 0.f};   // types  0..15
    floatx4 acc1 = {0.f, 0.f, 0.f, 0.f};   // types 16..31 (28..31 pad)

    // Type-staging slots: s in {tid, tid+256}; row = s>>3 (atom), q = s&7.
    const int r0 = tid >> 3,         q0 = tid & 7;
    const int r1 = (tid + 256) >> 3, q1 = tid & 7;  // same q, rows 32..63

    for (int k0 = 0; k0 < cnt; k0 += KB) {
        const int kmax = (cnt - k0 < KB) ? (cnt - k0) : KB;

        // ---- Issue type-row loads early (T14); zero-fill invalid slots ----
        float4 tv0 = make_float4(0.f, 0.f, 0.f, 0.f);
        float4 tv1 = tv0;
        if (q0 < 7 && r0 < kmax)
            tv0 = *(const float4*)(types + s_ai[k0 + r0] * NT + q0 * 4);
        if (q1 < 7 && r1 < kmax)
            tv1 = *(const float4*)(types + s_ai[k0 + r1] * NT + q1 * 4);

        // ---- Stage A: wave w computes+packs val rows [w*16, w*16+16) ----
        unsigned pk[8];
        #pragma unroll
        for (int jj = 0; jj < 8; ++jj) {
            float v[2];
            #pragma unroll
            for (int h = 0; h < 2; ++h) {
                int row = w * 16 + 2 * jj + h;
                float vv = 0.0f;
                if (row < kmax) {                    // wave-uniform
                    float4 at = s_atom[k0 + row];
                    float dx = gx - at.x;
                    float dy = gy - at.y;
                    float dz = gz - at.z;
                    float d2 = fmaf(dx, dx, fmaf(dy, dy, dz * dz));
                    float dr2 = d2 * at.w;
                    float g  = __expf(-2.0f * dr2);
                    float dr = sqrtf(dr2);
                    float q  = INV_E2 * fmaf(4.0f, dr2, fmaf(-12.0f, dr, 9.0f));
                    vv = (dr2 < 1.0f) ? g : ((dr2 < 2.25f) ? q : 0.0f);
                }
                v[h] = vv;
            }
            pk[jj] = (unsigned)f2bf(v[0]) | ((unsigned)f2bf(v[1]) << 16);
        }
        *(uint4*)&s_val[lane * KPAD + w * 16]     = *(uint4*)&pk[0];
        *(uint4*)&s_val[lane * KPAD + w * 16 + 8] = *(uint4*)&pk[4];

        // ---- Transposed type write [type][atom]; q==7 slots zero rows 28..31 ----
        {
            const float* e0 = &tv0.x;
            const float* e1 = &tv1.x;
            #pragma unroll
            for (int i = 0; i < 4; ++i) {
                s_tT[(q0 * 4 + i) * KPAD + r0] = f2bf(e0[i]);
                s_tT[(q1 * 4 + i) * KPAD + r1] = f2bf(e1[i]);
            }
        }
        __syncthreads();

        // ---- Stage B: MFMA — C[cell-tile w][types] += V-tile * T-tile ----
        #pragma unroll
        for (int ks = 0; ks < 2; ++ks) {
            int ko = ks * 32 + lg * 8;
            short8 afr = *(const short8*)&s_val[(w * 16 + lm) * KPAD + ko];
            short8 b0  = *(const short8*)&s_tT[lm * KPAD + ko];
            short8 b1  = *(const short8*)&s_tT[(16 + lm) * KPAD + ko];
            acc0 = __builtin_amdgcn_mfma_f32_16x16x32_bf16(afr, b0, acc0, 0, 0, 0);
            acc1 = __builtin_amdgcn_mfma_f32_16x16x32_bf16(afr, b1, acc1, 0, 0, 0);
        }
        __syncthreads();
    }

    // ---- Epilogue: acc -> LDS -> coalesced stores ----
    #pragma unroll
    for (int r = 0; r < 4; ++r) {
        int cellO = w * 16 + lg * 4 + r;
        s_out[cellO * 33 + lm]      = acc0[r];
        s_out[cellO * 33 + 16 + lm] = acc1[r];
    }
    __syncthreads();

    #pragma unroll
    for (int i = 0; i < 7; ++i) {
        int idx = i * 256 + tid;                 // < 1792 = 28*64
        int t = idx >> 6;
        int c = idx & 63;
        int z = c & 15, y = (c >> 4) & 1, x = c >> 5;
        int gidx = (tx * TXC + x) * GR2 + (ty * TYC + y) * GR + tz * TZC + z;
        out[t * GR3 + gidx] = s_out[c * 33 + t];
    }
}

extern "C" void kernel_launch(void* const* d_in, const int* in_sizes, int n_in,
                              void* d_out, int out_size, void* d_ws, size_t ws_size,
                              hipStream_t stream) {
    const float* center = (const float*)d_in[0];
    const float* coords = (const float*)d_in[1];
    const float* types  = (const float*)d_in[2];
    const float* radii  = (const float*)d_in[3];
    float* out = (float*)d_out;

    c2g_kernel<<<dim3(NBLK), dim3(256), 0, stream>>>(center, coords, types, radii, out);
}